// Round 10
// baseline (31.378 us; speedup 1.0000x reference)
//
#include <hip/hip_runtime.h>
#include <math.h>

#define NN 512
#define DD 512
#define HH 64
#define OUTC 32

// ws layout (floats):
//   P1T  [H][N]   @ 0      (32768)   col-major: P1T[h][j]
//   P2B  [N][H]   @ 32768  (32768)   row-major
//   XW   [N][OUT] @ 65536  (16384)   row-major
//   RDV  [N]      @ 81920  (512)
//   CTR  (int)    @ 82432            producer-consumer counter (k1 zeroes it)

// ------------------------------- K1 ----------------------------------------
// C[512][160] = F @ [W1a | W1b | gcn_w], split-K 32, 4 cols x 4 rows/thread.
template<int STRIDE>
__device__ __forceinline__ void dotrows(const float* __restrict__ fp,
                                        const float* __restrict__ wp,
                                        float4 acc[4])
{
    float4 fr[4][4];
    #pragma unroll
    for (int r = 0; r < 4; ++r)
        #pragma unroll
        for (int q = 0; q < 4; ++q)
            fr[r][q] = *(const float4*)(fp + (size_t)r * DD + 4 * q);

    #pragma unroll
    for (int q = 0; q < 16; ++q) {
        float4 w = *(const float4*)(wp + (size_t)q * STRIDE);
        #pragma unroll
        for (int r = 0; r < 4; ++r) {
            float f = (q < 4 ? (q == 0 ? fr[r][0].x : q == 1 ? fr[r][0].y : q == 2 ? fr[r][0].z : fr[r][0].w)
                     : q < 8 ? (q == 4 ? fr[r][1].x : q == 5 ? fr[r][1].y : q == 6 ? fr[r][1].z : fr[r][1].w)
                     : q < 12 ? (q == 8 ? fr[r][2].x : q == 9 ? fr[r][2].y : q == 10 ? fr[r][2].z : fr[r][2].w)
                     : (q == 12 ? fr[r][3].x : q == 13 ? fr[r][3].y : q == 14 ? fr[r][3].z : fr[r][3].w));
            acc[r].x = fmaf(f, w.x, acc[r].x);
            acc[r].y = fmaf(f, w.y, acc[r].y);
            acc[r].z = fmaf(f, w.z, acc[r].z);
            acc[r].w = fmaf(f, w.w, acc[r].w);
        }
    }
}

__global__ __launch_bounds__(256) void k1_gemm(
    const float* __restrict__ features,
    const float* __restrict__ rel_w1,
    const float* __restrict__ rel_b1,
    const float* __restrict__ gcn_w,
    float* __restrict__ p1t,
    float* __restrict__ p2b,
    float* __restrict__ xw,
    int* __restrict__ ctr)
{
    __shared__ float sred[4][32][33];
    const int t  = threadIdx.x;
    const int tq = t & 7;
    const int kc = t >> 3;
    const int cg = blockIdx.x;
    const int i0 = blockIdx.y * 4;

    if (cg == 0 && blockIdx.y == 0 && t == 0) *ctr = 0;   // published at dispatch edge

    const float* fp = features + (size_t)i0 * DD + kc * 16;

    float4 acc[4];
    #pragma unroll
    for (int r = 0; r < 4; ++r) acc[r] = make_float4(0.f, 0.f, 0.f, 0.f);

    if (cg < 2)
        dotrows<HH>(fp, rel_w1 + cg * 32 + tq * 4 + (size_t)kc * 16 * HH, acc);
    else if (cg < 4)
        dotrows<HH>(fp, rel_w1 + (size_t)DD * HH + (cg - 2) * 32 + tq * 4
                        + (size_t)kc * 16 * HH, acc);
    else
        dotrows<OUTC>(fp, gcn_w + tq * 4 + (size_t)kc * 16 * OUTC, acc);

    #pragma unroll
    for (int r = 0; r < 4; ++r) {
        sred[r][kc][tq * 4 + 0] = acc[r].x;
        sred[r][kc][tq * 4 + 1] = acc[r].y;
        sred[r][kc][tq * 4 + 2] = acc[r].z;
        sred[r][kc][tq * 4 + 3] = acc[r].w;
    }
    __syncthreads();

    if (t < 128) {
        const int r = t >> 5, c = t & 31;
        const int i = i0 + r;
        float s = 0.f;
        #pragma unroll
        for (int k = 0; k < 32; ++k) s += sred[r][k][c];
        if (cg < 2) {
            p1t[(size_t)(cg * 32 + c) * NN + i] = s;
        } else if (cg < 4) {
            int h = (cg - 2) * 32 + c;
            p2b[(size_t)i * HH + h] = s + rel_b1[h];
        } else {
            xw[(size_t)i * OUTC + c] = s;
        }
    }
}

// ------------------------------- KBC ----------------------------------------
// 512 blocks x 512 thr. Blocks 0..255 = B (adjacency rows 2b,2b+1 + rdv,
// then release ctr). Blocks 256..511 = C (acquire ctr==256, then normalize
// rows 2(b-256),+1 and matvec + BN + ReLU).
// Co-residency: 512 blocks x 8 waves = 4096 waves; launch_bounds(512,4)
// caps VGPR<=128 -> >=2 blocks/CU -> all resident; LDS ~11KB/block.
__global__ __launch_bounds__(512, 4) void kbc(
    const float* __restrict__ p1t,
    const float* __restrict__ p2b,
    const float* __restrict__ rel_w2,
    const float* __restrict__ rel_b2,
    const float* __restrict__ xw,
    const float* __restrict__ gcn_b,
    const float* __restrict__ bn_gamma,
    const float* __restrict__ bn_beta,
    float* __restrict__ rdv,
    float* __restrict__ outx,
    float* __restrict__ outA,
    int* __restrict__ ctr)
{
    const int t   = threadIdx.x;
    const int bid = blockIdx.x;

    if (bid < 256) {
        // =============== B: adjacency row pair + rowsum ===============
        __shared__ float sp2[2][HH];
        __shared__ float sw2[HH];
        __shared__ float sredB[2][8];
        const int i0 = bid * 2;

        if (t < HH)            sp2[0][t] = p2b[(size_t)i0 * HH + t];
        else if (t < 2 * HH)   sp2[1][t - HH] = p2b[(size_t)(i0 + 1) * HH + (t - HH)];
        else if (t < 3 * HH)   sw2[t - 2 * HH] = rel_w2[t - 2 * HH];
        __syncthreads();

        float a0 = rel_b2[0], a1 = a0;
        #pragma unroll
        for (int k = 0; k < HH; ++k) {
            float pv = p1t[(size_t)k * NN + t];    // coalesced per wave
            float w  = sw2[k];
            a0 = fmaf(fmaxf(pv + sp2[0][k], 0.f), w, a0);
            a1 = fmaf(fmaxf(pv + sp2[1][k], 0.f), w, a1);
        }
        a0 = 1.f / (1.f + expf(-a0));
        a1 = 1.f / (1.f + expf(-a1));
        if (t == i0)     a0 += 1.f;
        if (t == i0 + 1) a1 += 1.f;
        outA[(size_t)i0 * NN + t]       = a0;      // raw; C normalizes
        outA[(size_t)(i0 + 1) * NN + t] = a1;

        float rs0 = a0, rs1 = a1;
        #pragma unroll
        for (int off = 32; off > 0; off >>= 1) {
            rs0 += __shfl_down(rs0, off, 64);
            rs1 += __shfl_down(rs1, off, 64);
        }
        const int wv = t >> 6, ln = t & 63;
        if (ln == 0) { sredB[0][wv] = rs0; sredB[1][wv] = rs1; }
        __syncthreads();
        if (t < 2) {
            float s = 0.f;
            #pragma unroll
            for (int w = 0; w < 8; ++w) s += sredB[t][w];
            rdv[i0 + t] = 1.0f / sqrtf(s + 1.0f);
        }
        __syncthreads();                           // drains this block's stores
        if (t == 0) {
            __threadfence();                       // release
            atomicAdd(ctr, 1);
        }
    } else {
        // =============== C: normalize + A@XW + BN + ReLU ===============
        __shared__ float sdv[NN];
        __shared__ float sA[2][NN];
        __shared__ float sredC[2][16][33];
        const int i0 = (bid - 256) * 2;

        if (t == 0) {
            while (atomicAdd(ctr, 0) < 256) { __builtin_amdgcn_s_sleep(2); }
            __threadfence();                       // acquire
        }
        __syncthreads();

        sdv[t] = rdv[t];
        __syncthreads();

        const float dj = sdv[t];
        float an0 = outA[(size_t)i0 * NN + t]       * (sdv[i0] * dj);
        float an1 = outA[(size_t)(i0 + 1) * NN + t] * (sdv[i0 + 1] * dj);
        outA[(size_t)i0 * NN + t]       = an0;
        outA[(size_t)(i0 + 1) * NN + t] = an1;
        sA[0][t] = an0;
        sA[1][t] = an1;
        __syncthreads();

        const int o  = t & 31;
        const int ch = t >> 5;                     // 16 chunks of 32 j
        float acc0 = 0.f, acc1 = 0.f;
        #pragma unroll
        for (int jj = 0; jj < 32; ++jj) {
            int j = ch * 32 + jj;
            float xv = xw[(size_t)j * OUTC + o];   // 128B per 32-lane group
            acc0 = fmaf(sA[0][j], xv, acc0);
            acc1 = fmaf(sA[1][j], xv, acc1);
        }
        sredC[0][ch][o] = acc0;
        sredC[1][ch][o] = acc1;
        __syncthreads();

        if (t < 64) {
            const int rr = t >> 5, oc = t & 31;
            float v = gcn_b[oc];
            #pragma unroll
            for (int c = 0; c < 16; ++c) v += sredC[rr][c][oc];
            const float invs = 1.0f / sqrtf(1.0f + 1e-5f);
            v = bn_gamma[oc] * v * invs + bn_beta[oc];
            outx[(size_t)(i0 + rr) * OUTC + oc] = fmaxf(v, 0.f);
        }
    }
}

extern "C" void kernel_launch(void* const* d_in, const int* in_sizes, int n_in,
                              void* d_out, int out_size, void* d_ws, size_t ws_size,
                              hipStream_t stream) {
    const float* features = (const float*)d_in[0];
    const float* rel_w1   = (const float*)d_in[1];
    const float* rel_b1   = (const float*)d_in[2];
    const float* rel_w2   = (const float*)d_in[3];
    const float* rel_b2   = (const float*)d_in[4];
    const float* gcn_w    = (const float*)d_in[5];
    const float* gcn_b    = (const float*)d_in[6];
    const float* bn_gamma = (const float*)d_in[7];
    const float* bn_beta  = (const float*)d_in[8];

    float* out  = (float*)d_out;
    float* outx = out;                 // (512, 32)
    float* outA = out + NN * OUTC;     // (512, 512)

    float* ws  = (float*)d_ws;
    float* p1t = ws;                   // [64][512] col-major
    float* p2b = ws + 32768;           // [512][64]
    float* xw  = ws + 65536;           // [512][32] row-major
    float* rdv = ws + 81920;           // [512]
    int*   ctr = (int*)(ws + 82432);

    hipLaunchKernelGGL(k1_gemm, dim3(5, 128), dim3(256), 0, stream,
                       features, rel_w1, rel_b1, gcn_w, p1t, p2b, xw, ctr);
    hipLaunchKernelGGL(kbc, dim3(512), dim3(512), 0, stream,
                       p1t, p2b, rel_w2, rel_b2, xw,
                       gcn_b, bn_gamma, bn_beta, rdv, outx, outA, ctr);
}

// Round 11
// 29.800 us; speedup vs baseline: 1.0529x; 1.0529x over previous
//
#include <hip/hip_runtime.h>
#include <math.h>

#define NN 512
#define DD 512
#define HH 64
#define OUTC 32

// ws layout (floats):
//   P1T  [H][N]   @ 0      (32768)   col-major: P1T[h][j]
//   P2B  [N][H]   @ 32768  (32768)   row-major
//   XW   [N][OUT] @ 65536  (16384)   row-major
//   RDV  [N]      @ 81920  (512)
//   CTR  (int)    @ 82432            soft-barrier counter (k1 zeroes it)

// ------------------------------- K1 ----------------------------------------
// C[512][160] = F @ [W1a | W1b | gcn_w], split-K 32, 4 cols x 4 rows/thread.
template<int STRIDE>
__device__ __forceinline__ void dotrows(const float* __restrict__ fp,
                                        const float* __restrict__ wp,
                                        float4 acc[4])
{
    float4 fr[4][4];
    #pragma unroll
    for (int r = 0; r < 4; ++r)
        #pragma unroll
        for (int q = 0; q < 4; ++q)
            fr[r][q] = *(const float4*)(fp + (size_t)r * DD + 4 * q);

    #pragma unroll
    for (int q = 0; q < 16; ++q) {
        float4 w = *(const float4*)(wp + (size_t)q * STRIDE);
        #pragma unroll
        for (int r = 0; r < 4; ++r) {
            float f = (q < 4 ? (q == 0 ? fr[r][0].x : q == 1 ? fr[r][0].y : q == 2 ? fr[r][0].z : fr[r][0].w)
                     : q < 8 ? (q == 4 ? fr[r][1].x : q == 5 ? fr[r][1].y : q == 6 ? fr[r][1].z : fr[r][1].w)
                     : q < 12 ? (q == 8 ? fr[r][2].x : q == 9 ? fr[r][2].y : q == 10 ? fr[r][2].z : fr[r][2].w)
                     : (q == 12 ? fr[r][3].x : q == 13 ? fr[r][3].y : q == 14 ? fr[r][3].z : fr[r][3].w));
            acc[r].x = fmaf(f, w.x, acc[r].x);
            acc[r].y = fmaf(f, w.y, acc[r].y);
            acc[r].z = fmaf(f, w.z, acc[r].z);
            acc[r].w = fmaf(f, w.w, acc[r].w);
        }
    }
}

__global__ __launch_bounds__(256) void k1_gemm(
    const float* __restrict__ features,
    const float* __restrict__ rel_w1,
    const float* __restrict__ rel_b1,
    const float* __restrict__ gcn_w,
    float* __restrict__ p1t,
    float* __restrict__ p2b,
    float* __restrict__ xw,
    int* __restrict__ ctr)
{
    __shared__ float sred[4][32][33];
    const int t  = threadIdx.x;
    const int tq = t & 7;
    const int kc = t >> 3;
    const int cg = blockIdx.x;
    const int i0 = blockIdx.y * 4;

    if (cg == 0 && blockIdx.y == 0 && t == 0) *ctr = 0;   // published at graph edge

    const float* fp = features + (size_t)i0 * DD + kc * 16;

    float4 acc[4];
    #pragma unroll
    for (int r = 0; r < 4; ++r) acc[r] = make_float4(0.f, 0.f, 0.f, 0.f);

    if (cg < 2)
        dotrows<HH>(fp, rel_w1 + cg * 32 + tq * 4 + (size_t)kc * 16 * HH, acc);
    else if (cg < 4)
        dotrows<HH>(fp, rel_w1 + (size_t)DD * HH + (cg - 2) * 32 + tq * 4
                        + (size_t)kc * 16 * HH, acc);
    else
        dotrows<OUTC>(fp, gcn_w + tq * 4 + (size_t)kc * 16 * OUTC, acc);

    #pragma unroll
    for (int r = 0; r < 4; ++r) {
        sred[r][kc][tq * 4 + 0] = acc[r].x;
        sred[r][kc][tq * 4 + 1] = acc[r].y;
        sred[r][kc][tq * 4 + 2] = acc[r].z;
        sred[r][kc][tq * 4 + 3] = acc[r].w;
    }
    __syncthreads();

    if (t < 128) {
        const int r = t >> 5, c = t & 31;
        const int i = i0 + r;
        float s = 0.f;
        #pragma unroll
        for (int k = 0; k < 32; ++k) s += sred[r][k][c];
        if (cg < 2) {
            p1t[(size_t)(cg * 32 + c) * NN + i] = s;
        } else if (cg < 4) {
            int h = (cg - 2) * 32 + c;
            p2b[(size_t)i * HH + h] = s + rel_b1[h];
        } else {
            xw[(size_t)i * OUTC + c] = s;
        }
    }
}

// ------------------------------- K23 ----------------------------------------
// 256 blocks x 512 thr; block b owns rows i0=2b, i0+1 end-to-end.
// Phase B: adjacency rows (kept in REGISTERS) + rdv -> global.
// Soft barrier: release fence + atomicAdd; all blocks poll to 256 (grid fits
// residency: 256 blocks <= 256 CUs, 8 waves & ~11KB LDS each -> all scheduled).
// Phase C: normalize from registers, write outA once, matvec + BN + ReLU.
__global__ __launch_bounds__(512) void k23(
    const float* __restrict__ p1t,
    const float* __restrict__ p2b,
    const float* __restrict__ rel_w2,
    const float* __restrict__ rel_b2,
    const float* __restrict__ xw,
    const float* __restrict__ gcn_b,
    const float* __restrict__ bn_gamma,
    const float* __restrict__ bn_beta,
    float* __restrict__ rdv,
    float* __restrict__ outx,
    float* __restrict__ outA,
    int* __restrict__ ctr)
{
    __shared__ float sp2[2][HH];
    __shared__ float sw2[HH];
    __shared__ float sredB[2][8];
    __shared__ float sdv[NN];
    __shared__ float sA[2][NN];
    __shared__ float sredC[2][16][33];

    const int t  = threadIdx.x;       // j
    const int i0 = blockIdx.x * 2;

    // ---------------- Phase B: adjacency rows + rowsum ----------------
    if (t < HH)            sp2[0][t] = p2b[(size_t)i0 * HH + t];
    else if (t < 2 * HH)   sp2[1][t - HH] = p2b[(size_t)(i0 + 1) * HH + (t - HH)];
    else if (t < 3 * HH)   sw2[t - 2 * HH] = rel_w2[t - 2 * HH];
    __syncthreads();

    float a0 = rel_b2[0], a1 = a0;
    #pragma unroll
    for (int k = 0; k < HH; ++k) {
        float pv = p1t[(size_t)k * NN + t];        // 2KB coalesced per block
        float w  = sw2[k];
        a0 = fmaf(fmaxf(pv + sp2[0][k], 0.f), w, a0);
        a1 = fmaf(fmaxf(pv + sp2[1][k], 0.f), w, a1);
    }
    a0 = 1.f / (1.f + expf(-a0));
    a1 = 1.f / (1.f + expf(-a1));
    if (t == i0)     a0 += 1.f;
    if (t == i0 + 1) a1 += 1.f;
    // a0,a1 stay in registers across the barrier (no araw round-trip)

    float rs0 = a0, rs1 = a1;
    #pragma unroll
    for (int off = 32; off > 0; off >>= 1) {
        rs0 += __shfl_down(rs0, off, 64);
        rs1 += __shfl_down(rs1, off, 64);
    }
    const int wv = t >> 6, ln = t & 63;
    if (ln == 0) { sredB[0][wv] = rs0; sredB[1][wv] = rs1; }
    __syncthreads();
    if (t < 2) {
        float s = 0.f;
        #pragma unroll
        for (int w = 0; w < 8; ++w) s += sredB[t][w];
        rdv[i0 + t] = 1.0f / sqrtf(s + 1.0f);
    }
    __syncthreads();                               // rdv stores issued

    // ---------------- soft barrier (all 256 blocks) ----------------
    if (t == 0) {
        __threadfence();                           // release rdv
        atomicAdd(ctr, 1);
        while (atomicAdd(ctr, 0) < 256) { __builtin_amdgcn_s_sleep(8); }
        __threadfence();                           // acquire others' rdv
    }
    __syncthreads();

    // ---------------- Phase C: normalize + A@XW + BN + ReLU ----------------
    sdv[t] = rdv[t];
    __syncthreads();

    const float dj  = sdv[t];
    const float an0 = a0 * (sdv[i0] * dj);
    const float an1 = a1 * (sdv[i0 + 1] * dj);
    outA[(size_t)i0 * NN + t]       = an0;         // written once, final
    outA[(size_t)(i0 + 1) * NN + t] = an1;
    sA[0][t] = an0;
    sA[1][t] = an1;
    __syncthreads();

    const int o  = t & 31;
    const int ch = t >> 5;                         // 16 chunks of 32 j
    float acc0 = 0.f, acc1 = 0.f;
    #pragma unroll
    for (int jj = 0; jj < 32; ++jj) {
        int j = ch * 32 + jj;
        float xv = xw[(size_t)j * OUTC + o];       // 128B per 32-lane group
        acc0 = fmaf(sA[0][j], xv, acc0);
        acc1 = fmaf(sA[1][j], xv, acc1);
    }
    sredC[0][ch][o] = acc0;
    sredC[1][ch][o] = acc1;
    __syncthreads();

    if (t < 64) {
        const int rr = t >> 5, oc = t & 31;
        float v = gcn_b[oc];
        #pragma unroll
        for (int c = 0; c < 16; ++c) v += sredC[rr][c][oc];
        const float invs = 1.0f / sqrtf(1.0f + 1e-5f);
        v = bn_gamma[oc] * v * invs + bn_beta[oc];
        outx[(size_t)(i0 + rr) * OUTC + oc] = fmaxf(v, 0.f);
    }
}

extern "C" void kernel_launch(void* const* d_in, const int* in_sizes, int n_in,
                              void* d_out, int out_size, void* d_ws, size_t ws_size,
                              hipStream_t stream) {
    const float* features = (const float*)d_in[0];
    const float* rel_w1   = (const float*)d_in[1];
    const float* rel_b1   = (const float*)d_in[2];
    const float* rel_w2   = (const float*)d_in[3];
    const float* rel_b2   = (const float*)d_in[4];
    const float* gcn_w    = (const float*)d_in[5];
    const float* gcn_b    = (const float*)d_in[6];
    const float* bn_gamma = (const float*)d_in[7];
    const float* bn_beta  = (const float*)d_in[8];

    float* out  = (float*)d_out;
    float* outx = out;                 // (512, 32)
    float* outA = out + NN * OUTC;     // (512, 512)

    float* ws  = (float*)d_ws;
    float* p1t = ws;                   // [64][512] col-major
    float* p2b = ws + 32768;           // [512][64]
    float* xw  = ws + 65536;           // [512][32] row-major
    float* rdv = ws + 81920;           // [512]
    int*   ctr = (int*)(ws + 82432);

    hipLaunchKernelGGL(k1_gemm, dim3(5, 128), dim3(256), 0, stream,
                       features, rel_w1, rel_b1, gcn_w, p1t, p2b, xw, ctr);
    hipLaunchKernelGGL(k23, dim3(256), dim3(512), 0, stream,
                       p1t, p2b, rel_w2, rel_b2, xw,
                       gcn_b, bn_gamma, bn_beta, rdv, outx, outA, ctr);
}

// Round 12
// 17.919 us; speedup vs baseline: 1.7511x; 1.6631x over previous
//
#include <hip/hip_runtime.h>
#include <math.h>

#define NN 512
#define DD 512
#define HH 64
#define OUTC 32

// ws layout (floats):
//   P1T  [H][N]   @ 0      (32768)   col-major: P1T[h][j]
//   P2B  [N][H]   @ 32768  (32768)   row-major
//   XW   [N][OUT] @ 65536  (16384)   row-major
//   RDV  [N]      @ 81920  (512)

// ------------------------------- K1 ----------------------------------------
// C[512][160] = F @ [W1a | W1b | gcn_w], split-K 32, 4 cols x 4 rows/thread.
template<int STRIDE>
__device__ __forceinline__ void dotrows(const float* __restrict__ fp,
                                        const float* __restrict__ wp,
                                        float4 acc[4])
{
    float4 fr[4][4];
    #pragma unroll
    for (int r = 0; r < 4; ++r)
        #pragma unroll
        for (int q = 0; q < 4; ++q)
            fr[r][q] = *(const float4*)(fp + (size_t)r * DD + 4 * q);

    #pragma unroll
    for (int q = 0; q < 16; ++q) {
        float4 w = *(const float4*)(wp + (size_t)q * STRIDE);
        #pragma unroll
        for (int r = 0; r < 4; ++r) {
            float f = (q < 4 ? (q == 0 ? fr[r][0].x : q == 1 ? fr[r][0].y : q == 2 ? fr[r][0].z : fr[r][0].w)
                     : q < 8 ? (q == 4 ? fr[r][1].x : q == 5 ? fr[r][1].y : q == 6 ? fr[r][1].z : fr[r][1].w)
                     : q < 12 ? (q == 8 ? fr[r][2].x : q == 9 ? fr[r][2].y : q == 10 ? fr[r][2].z : fr[r][2].w)
                     : (q == 12 ? fr[r][3].x : q == 13 ? fr[r][3].y : q == 14 ? fr[r][3].z : fr[r][3].w));
            acc[r].x = fmaf(f, w.x, acc[r].x);
            acc[r].y = fmaf(f, w.y, acc[r].y);
            acc[r].z = fmaf(f, w.z, acc[r].z);
            acc[r].w = fmaf(f, w.w, acc[r].w);
        }
    }
}

__global__ __launch_bounds__(256) void k1_gemm(
    const float* __restrict__ features,
    const float* __restrict__ rel_w1,
    const float* __restrict__ rel_b1,
    const float* __restrict__ gcn_w,
    float* __restrict__ p1t,
    float* __restrict__ p2b,
    float* __restrict__ xw)
{
    __shared__ float sred[4][32][33];
    const int t  = threadIdx.x;
    const int tq = t & 7;
    const int kc = t >> 3;
    const int cg = blockIdx.x;
    const int i0 = blockIdx.y * 4;

    const float* fp = features + (size_t)i0 * DD + kc * 16;

    float4 acc[4];
    #pragma unroll
    for (int r = 0; r < 4; ++r) acc[r] = make_float4(0.f, 0.f, 0.f, 0.f);

    if (cg < 2)
        dotrows<HH>(fp, rel_w1 + cg * 32 + tq * 4 + (size_t)kc * 16 * HH, acc);
    else if (cg < 4)
        dotrows<HH>(fp, rel_w1 + (size_t)DD * HH + (cg - 2) * 32 + tq * 4
                        + (size_t)kc * 16 * HH, acc);
    else
        dotrows<OUTC>(fp, gcn_w + tq * 4 + (size_t)kc * 16 * OUTC, acc);

    #pragma unroll
    for (int r = 0; r < 4; ++r) {
        sred[r][kc][tq * 4 + 0] = acc[r].x;
        sred[r][kc][tq * 4 + 1] = acc[r].y;
        sred[r][kc][tq * 4 + 2] = acc[r].z;
        sred[r][kc][tq * 4 + 3] = acc[r].w;
    }
    __syncthreads();

    if (t < 128) {
        const int r = t >> 5, c = t & 31;
        const int i = i0 + r;
        float s = 0.f;
        #pragma unroll
        for (int k = 0; k < 32; ++k) s += sred[r][k][c];
        if (cg < 2) {
            p1t[(size_t)(cg * 32 + c) * NN + i] = s;
        } else if (cg < 4) {
            int h = (cg - 2) * 32 + c;
            p2b[(size_t)i * HH + h] = s + rel_b1[h];
        } else {
            xw[(size_t)i * OUTC + c] = s;
        }
    }
}

// ------------------------------- K2 ----------------------------------------
// 2 rows/block (256 blocks x 512 thr), thread = col j.
// w2[k] and p2b[i0*HH+k] are WAVE-UNIFORM loads -> compiler scalarizes to
// s_load (SGPR operands, constant cache): zero LDS traffic in the hot loop.
__global__ __launch_bounds__(512) void k2_adj(
    const float* __restrict__ p1t,
    const float* __restrict__ p2b,
    const float* __restrict__ rel_w2,
    const float* __restrict__ rel_b2,
    float* __restrict__ araw,     // d_out A region (raw; normalized in k3)
    float* __restrict__ rdv)
{
    __shared__ float sred[2][8];
    const int t  = threadIdx.x;   // j
    const int i0 = blockIdx.x * 2;

    const float* p20 = p2b + (size_t)i0 * HH;
    const float* p21 = p20 + HH;

    float a0 = rel_b2[0], a1 = a0;
    #pragma unroll
    for (int k = 0; k < HH; ++k) {
        float pv = p1t[(size_t)k * NN + t];    // 256B coalesced per wave
        float w  = rel_w2[k];                  // uniform -> s_load
        a0 = fmaf(fmaxf(pv + p20[k], 0.f), w, a0);   // p2: uniform -> s_load
        a1 = fmaf(fmaxf(pv + p21[k], 0.f), w, a1);
    }
    a0 = 1.f / (1.f + expf(-a0));
    a1 = 1.f / (1.f + expf(-a1));
    if (t == i0)     a0 += 1.f;
    if (t == i0 + 1) a1 += 1.f;
    araw[(size_t)i0 * NN + t]       = a0;
    araw[(size_t)(i0 + 1) * NN + t] = a1;

    float rs0 = a0, rs1 = a1;
    #pragma unroll
    for (int off = 32; off > 0; off >>= 1) {
        rs0 += __shfl_down(rs0, off, 64);
        rs1 += __shfl_down(rs1, off, 64);
    }
    const int wv = t >> 6, ln = t & 63;
    if (ln == 0) { sred[0][wv] = rs0; sred[1][wv] = rs1; }
    __syncthreads();
    if (t < 2) {
        float s = 0.f;
        #pragma unroll
        for (int w = 0; w < 8; ++w) s += sred[t][w];
        rdv[i0 + t] = 1.0f / sqrtf(s + 1.0f);
    }
}

// ------------------------------- K3 ----------------------------------------
// 2 rows/block (256 blocks x 512 thr). Normalize both A rows (LDS-cached),
// matvec with each xw load feeding both rows, BN + ReLU.
__global__ __launch_bounds__(512) void k3_gcn(
    const float* __restrict__ xw,
    const float* __restrict__ rdv,
    const float* __restrict__ gcn_b,
    const float* __restrict__ bn_gamma,
    const float* __restrict__ bn_beta,
    float* __restrict__ outx,
    float* __restrict__ outA)
{
    __shared__ float sdv[NN];
    __shared__ float sA[2][NN];
    __shared__ float sredC[2][16][33];
    const int t  = threadIdx.x;   // j
    const int i0 = blockIdx.x * 2;

    sdv[t] = rdv[t];
    __syncthreads();

    const float dj  = sdv[t];
    const float an0 = outA[(size_t)i0 * NN + t]       * (sdv[i0] * dj);
    const float an1 = outA[(size_t)(i0 + 1) * NN + t] * (sdv[i0 + 1] * dj);
    outA[(size_t)i0 * NN + t]       = an0;
    outA[(size_t)(i0 + 1) * NN + t] = an1;
    sA[0][t] = an0;
    sA[1][t] = an1;
    __syncthreads();

    const int o  = t & 31;
    const int ch = t >> 5;        // 16 chunks of 32 j
    float acc0 = 0.f, acc1 = 0.f;
    #pragma unroll
    for (int jj = 0; jj < 32; ++jj) {
        int j = ch * 32 + jj;
        float xv = xw[(size_t)j * OUTC + o];   // 128B per 32-lane group
        acc0 = fmaf(sA[0][j], xv, acc0);
        acc1 = fmaf(sA[1][j], xv, acc1);
    }
    sredC[0][ch][o] = acc0;
    sredC[1][ch][o] = acc1;
    __syncthreads();

    if (t < 64) {
        const int rr = t >> 5, oc = t & 31;
        float v = gcn_b[oc];
        #pragma unroll
        for (int c = 0; c < 16; ++c) v += sredC[rr][c][oc];
        const float invs = 1.0f / sqrtf(1.0f + 1e-5f);
        v = bn_gamma[oc] * v * invs + bn_beta[oc];
        outx[(size_t)(i0 + rr) * OUTC + oc] = fmaxf(v, 0.f);
    }
}

extern "C" void kernel_launch(void* const* d_in, const int* in_sizes, int n_in,
                              void* d_out, int out_size, void* d_ws, size_t ws_size,
                              hipStream_t stream) {
    const float* features = (const float*)d_in[0];
    const float* rel_w1   = (const float*)d_in[1];
    const float* rel_b1   = (const float*)d_in[2];
    const float* rel_w2   = (const float*)d_in[3];
    const float* rel_b2   = (const float*)d_in[4];
    const float* gcn_w    = (const float*)d_in[5];
    const float* gcn_b    = (const float*)d_in[6];
    const float* bn_gamma = (const float*)d_in[7];
    const float* bn_beta  = (const float*)d_in[8];

    float* out  = (float*)d_out;
    float* outx = out;                 // (512, 32)
    float* outA = out + NN * OUTC;     // (512, 512)

    float* ws  = (float*)d_ws;
    float* p1t = ws;                   // [64][512] col-major
    float* p2b = ws + 32768;           // [512][64]
    float* xw  = ws + 65536;           // [512][32] row-major
    float* rdv = ws + 81920;           // [512]

    hipLaunchKernelGGL(k1_gemm, dim3(5, 128), dim3(256), 0, stream,
                       features, rel_w1, rel_b1, gcn_w, p1t, p2b, xw);
    hipLaunchKernelGGL(k2_adj, dim3(256), dim3(512), 0, stream,
                       p1t, p2b, rel_w2, rel_b2, outA, rdv);
    hipLaunchKernelGGL(k3_gcn, dim3(256), dim3(512), 0, stream,
                       xw, rdv, gcn_b, bn_gamma, bn_beta, outx, outA);
}

// Round 13
// 17.653 us; speedup vs baseline: 1.7775x; 1.0151x over previous
//
#include <hip/hip_runtime.h>
#include <math.h>

#define NN 512
#define DD 512
#define HH 64
#define OUTC 32

// ws layout (floats):
//   P1P  [16][512][4] @ 0     (32768)  packed: P1P[k4][j][s] = P1[4*k4+s][j]
//                                      -> k2 reads one float4 per 4 h-values
//   P2B  [N][H]   @ 32768  (32768)   row-major
//   XW   [N][OUT] @ 65536  (16384)   row-major
//   RDV  [N]      @ 81920  (512)

// ------------------------------- K1 ----------------------------------------
// C[512][160] = F @ [W1a | W1b | gcn_w], split-K 32, 4 cols x 4 rows per call,
// 8 rows/block via two calls sharing the W panel (halves W L2 traffic).
template<int STRIDE>
__device__ __forceinline__ void dotrows(const float* __restrict__ fp,
                                        const float* __restrict__ wp,
                                        float4 acc[4])
{
    float4 fr[4][4];
    #pragma unroll
    for (int r = 0; r < 4; ++r)
        #pragma unroll
        for (int q = 0; q < 4; ++q)
            fr[r][q] = *(const float4*)(fp + (size_t)r * DD + 4 * q);

    #pragma unroll
    for (int q = 0; q < 16; ++q) {
        float4 w = *(const float4*)(wp + (size_t)q * STRIDE);
        #pragma unroll
        for (int r = 0; r < 4; ++r) {
            float f = (q < 4 ? (q == 0 ? fr[r][0].x : q == 1 ? fr[r][0].y : q == 2 ? fr[r][0].z : fr[r][0].w)
                     : q < 8 ? (q == 4 ? fr[r][1].x : q == 5 ? fr[r][1].y : q == 6 ? fr[r][1].z : fr[r][1].w)
                     : q < 12 ? (q == 8 ? fr[r][2].x : q == 9 ? fr[r][2].y : q == 10 ? fr[r][2].z : fr[r][2].w)
                     : (q == 12 ? fr[r][3].x : q == 13 ? fr[r][3].y : q == 14 ? fr[r][3].z : fr[r][3].w));
            acc[r].x = fmaf(f, w.x, acc[r].x);
            acc[r].y = fmaf(f, w.y, acc[r].y);
            acc[r].z = fmaf(f, w.z, acc[r].z);
            acc[r].w = fmaf(f, w.w, acc[r].w);
        }
    }
}

__global__ __launch_bounds__(256) void k1_gemm(
    const float* __restrict__ features,
    const float* __restrict__ rel_w1,
    const float* __restrict__ rel_b1,
    const float* __restrict__ gcn_w,
    float* __restrict__ p1p,
    float* __restrict__ p2b,
    float* __restrict__ xw)
{
    __shared__ float sred[8][32][33];      // 33.8 KB
    const int t  = threadIdx.x;
    const int tq = t & 7;
    const int kc = t >> 3;
    const int cg = blockIdx.x;             // 0..4
    const int i0 = blockIdx.y * 8;         // 8 rows/block

    const float* fp = features + (size_t)i0 * DD + kc * 16;

    float4 acc[8];
    #pragma unroll
    for (int r = 0; r < 8; ++r) acc[r] = make_float4(0.f, 0.f, 0.f, 0.f);

    const float* wp;
    if (cg < 2)      wp = rel_w1 + cg * 32 + tq * 4 + (size_t)kc * 16 * HH;
    else if (cg < 4) wp = rel_w1 + (size_t)DD * HH + (cg - 2) * 32 + tq * 4
                          + (size_t)kc * 16 * HH;
    else             wp = gcn_w + tq * 4 + (size_t)kc * 16 * OUTC;

    if (cg < 4) {
        dotrows<HH>(fp, wp, acc);
        dotrows<HH>(fp + 4 * DD, wp, acc + 4);     // W re-read hits L1
    } else {
        dotrows<OUTC>(fp, wp, acc);
        dotrows<OUTC>(fp + 4 * DD, wp, acc + 4);
    }

    #pragma unroll
    for (int r = 0; r < 8; ++r) {
        sred[r][kc][tq * 4 + 0] = acc[r].x;
        sred[r][kc][tq * 4 + 1] = acc[r].y;
        sred[r][kc][tq * 4 + 2] = acc[r].z;
        sred[r][kc][tq * 4 + 3] = acc[r].w;
    }
    __syncthreads();

    {
        const int r = t >> 5, c = t & 31;          // 256 thr = 8 rows x 32 cols
        const int i = i0 + r;
        float s = 0.f;
        #pragma unroll
        for (int k = 0; k < 32; ++k) s += sred[r][k][c];
        if (cg < 2) {
            const int h = cg * 32 + c;
            // packed layout: p1p[(h>>2)*2048 + i*4 + (h&3)]
            p1p[(size_t)(h >> 2) * (NN * 4) + (size_t)i * 4 + (h & 3)] = s;
        } else if (cg < 4) {
            const int h = (cg - 2) * 32 + c;
            p2b[(size_t)i * HH + h] = s + rel_b1[h];
        } else {
            xw[(size_t)i * OUTC + c] = s;
        }
    }
}

// ------------------------------- K2 ----------------------------------------
// 2 rows/block (256 blocks x 512 thr), thread = col j.
// p1 via PACKED float4 loads (16/thread, 1KB/wave, coalesced); w2/p2b are
// wave-uniform -> s_load (no LDS in hot loop).
__global__ __launch_bounds__(512) void k2_adj(
    const float* __restrict__ p1p,
    const float* __restrict__ p2b,
    const float* __restrict__ rel_w2,
    const float* __restrict__ rel_b2,
    float* __restrict__ araw,     // d_out A region (raw; normalized in k3)
    float* __restrict__ rdv)
{
    __shared__ float sred[2][8];
    const int t  = threadIdx.x;   // j
    const int i0 = blockIdx.x * 2;

    const float* p20 = p2b + (size_t)i0 * HH;
    const float* p21 = p20 + HH;

    float a0 = rel_b2[0], a1 = a0;
    #pragma unroll
    for (int k4 = 0; k4 < 16; ++k4) {
        float4 pv = *(const float4*)(p1p + (size_t)k4 * (NN * 4) + (size_t)t * 4);
        const int kb = 4 * k4;
        float w0 = rel_w2[kb + 0], w1 = rel_w2[kb + 1];
        float w2 = rel_w2[kb + 2], w3 = rel_w2[kb + 3];
        a0 = fmaf(fmaxf(pv.x + p20[kb + 0], 0.f), w0, a0);
        a1 = fmaf(fmaxf(pv.x + p21[kb + 0], 0.f), w0, a1);
        a0 = fmaf(fmaxf(pv.y + p20[kb + 1], 0.f), w1, a0);
        a1 = fmaf(fmaxf(pv.y + p21[kb + 1], 0.f), w1, a1);
        a0 = fmaf(fmaxf(pv.z + p20[kb + 2], 0.f), w2, a0);
        a1 = fmaf(fmaxf(pv.z + p21[kb + 2], 0.f), w2, a1);
        a0 = fmaf(fmaxf(pv.w + p20[kb + 3], 0.f), w3, a0);
        a1 = fmaf(fmaxf(pv.w + p21[kb + 3], 0.f), w3, a1);
    }
    a0 = 1.f / (1.f + expf(-a0));
    a1 = 1.f / (1.f + expf(-a1));
    if (t == i0)     a0 += 1.f;
    if (t == i0 + 1) a1 += 1.f;
    araw[(size_t)i0 * NN + t]       = a0;
    araw[(size_t)(i0 + 1) * NN + t] = a1;

    float rs0 = a0, rs1 = a1;
    #pragma unroll
    for (int off = 32; off > 0; off >>= 1) {
        rs0 += __shfl_down(rs0, off, 64);
        rs1 += __shfl_down(rs1, off, 64);
    }
    const int wv = t >> 6, ln = t & 63;
    if (ln == 0) { sred[0][wv] = rs0; sred[1][wv] = rs1; }
    __syncthreads();
    if (t < 2) {
        float s = 0.f;
        #pragma unroll
        for (int w = 0; w < 8; ++w) s += sred[t][w];
        rdv[i0 + t] = 1.0f / sqrtf(s + 1.0f);
    }
}

// ------------------------------- K3 ----------------------------------------
// 2 rows/block (256 blocks x 512 thr). Normalize both A rows (LDS-cached),
// matvec with each xw load feeding both rows, BN + ReLU.
__global__ __launch_bounds__(512) void k3_gcn(
    const float* __restrict__ xw,
    const float* __restrict__ rdv,
    const float* __restrict__ gcn_b,
    const float* __restrict__ bn_gamma,
    const float* __restrict__ bn_beta,
    float* __restrict__ outx,
    float* __restrict__ outA)
{
    __shared__ float sdv[NN];
    __shared__ float sA[2][NN];
    __shared__ float sredC[2][16][33];
    const int t  = threadIdx.x;   // j
    const int i0 = blockIdx.x * 2;

    sdv[t] = rdv[t];
    __syncthreads();

    const float dj  = sdv[t];
    const float an0 = outA[(size_t)i0 * NN + t]       * (sdv[i0] * dj);
    const float an1 = outA[(size_t)(i0 + 1) * NN + t] * (sdv[i0 + 1] * dj);
    outA[(size_t)i0 * NN + t]       = an0;
    outA[(size_t)(i0 + 1) * NN + t] = an1;
    sA[0][t] = an0;
    sA[1][t] = an1;
    __syncthreads();

    const int o  = t & 31;
    const int ch = t >> 5;        // 16 chunks of 32 j
    float acc0 = 0.f, acc1 = 0.f;
    #pragma unroll
    for (int jj = 0; jj < 32; ++jj) {
        int j = ch * 32 + jj;
        float xv = xw[(size_t)j * OUTC + o];   // 128B per 32-lane group
        acc0 = fmaf(sA[0][j], xv, acc0);
        acc1 = fmaf(sA[1][j], xv, acc1);
    }
    sredC[0][ch][o] = acc0;
    sredC[1][ch][o] = acc1;
    __syncthreads();

    if (t < 64) {
        const int rr = t >> 5, oc = t & 31;
        float v = gcn_b[oc];
        #pragma unroll
        for (int c = 0; c < 16; ++c) v += sredC[rr][c][oc];
        const float invs = 1.0f / sqrtf(1.0f + 1e-5f);
        v = bn_gamma[oc] * v * invs + bn_beta[oc];
        outx[(size_t)(i0 + rr) * OUTC + oc] = fmaxf(v, 0.f);
    }
}

extern "C" void kernel_launch(void* const* d_in, const int* in_sizes, int n_in,
                              void* d_out, int out_size, void* d_ws, size_t ws_size,
                              hipStream_t stream) {
    const float* features = (const float*)d_in[0];
    const float* rel_w1   = (const float*)d_in[1];
    const float* rel_b1   = (const float*)d_in[2];
    const float* rel_w2   = (const float*)d_in[3];
    const float* rel_b2   = (const float*)d_in[4];
    const float* gcn_w    = (const float*)d_in[5];
    const float* gcn_b    = (const float*)d_in[6];
    const float* bn_gamma = (const float*)d_in[7];
    const float* bn_beta  = (const float*)d_in[8];

    float* out  = (float*)d_out;
    float* outx = out;                 // (512, 32)
    float* outA = out + NN * OUTC;     // (512, 512)

    float* ws  = (float*)d_ws;
    float* p1p = ws;                   // [16][512][4] packed
    float* p2b = ws + 32768;           // [512][64]
    float* xw  = ws + 65536;           // [512][32] row-major
    float* rdv = ws + 81920;           // [512]

    hipLaunchKernelGGL(k1_gemm, dim3(5, 64), dim3(256), 0, stream,
                       features, rel_w1, rel_b1, gcn_w, p1p, p2b, xw);
    hipLaunchKernelGGL(k2_adj, dim3(256), dim3(512), 0, stream,
                       p1p, p2b, rel_w2, rel_b2, outA, rdv);
    hipLaunchKernelGGL(k3_gcn, dim3(256), dim3(512), 0, stream,
                       xw, rdv, gcn_b, bn_gamma, bn_beta, outx, outA);
}